// Round 5
// baseline (116.430 us; speedup 1.0000x reference)
//
#include <hip/hip_runtime.h>

// PiecewiseDiscontinuousPolynomial
//   x: (B=32768, F=256) f32 in [-1,1)
//   w: (F=256, F*N*SEG=40960) f32 -- but only columns [0,160) are ever used:
//      cols = id_min[b,0]*5 + j,  id_min[b,0] in [0,32)
//   out[b,f] = sum_j basis_j(x_in[b,f]) * w[f, seg0(b)*5+j]
//
// Strategy:
//   prep kernel: transpose + prescale the used 160KB slice of w into d_ws:
//       wt[c*256 + f] = w[f*40960 + c] * C[c%5],  C = 1/prod(X_j - X_m)
//   main kernel: 1 wave per row (64 lanes x float4 = 256 features).
//       seg0 is wave-uniform (from x[b,0] via __shfl) -> coalesced float4
//       weight loads from wt. Lagrange numerators via prefix/suffix products
//       (denominators already folded into wt) -> ~25 VALU ops/element.
//   x / out are streamed with nontemporal hints (touched exactly once);
//   NOTE: __builtin_nontemporal_* requires a clang-native vector type, not
//   HIP's float4 class -> use ext_vector_type(4).

#define IN_F  256
#define NW    40960   // w leading dimension (columns)
#define NSEG  32
#define NNODE 5
#define USED_COLS (NSEG * NNODE)   // 160

typedef float f32x4 __attribute__((ext_vector_type(4)));

__global__ __launch_bounds__(256) void pdp_prep(const float* __restrict__ w,
                                                float* __restrict__ wt) {
    int tid = blockIdx.x * blockDim.x + threadIdx.x;
    if (tid >= USED_COLS * IN_F) return;
    int f = tid / USED_COLS;   // 0..255
    int c = tid % USED_COLS;   // 0..159  (reads are contiguous in c per f)
    int j = c % NNODE;
    // c_j = 1 / prod_{m!=j}(X_j - X_m),  X = {-1,-0.5,0,0.5,1}
    float cj = (j == 2) ? 4.0f : ((j == 1 || j == 3) ? (-8.0f / 3.0f) : (2.0f / 3.0f));
    wt[c * IN_F + f] = w[(size_t)f * NW + c] * cj;
}

__device__ __forceinline__ float pdp_eval(float xe,
                                          float w0, float w1, float w2,
                                          float w3, float w4) {
    // per-element segment & local coordinate (bitwise == reference:
    // all scalings are exact powers of two)
    float idf  = floorf((xe + 1.0f) * 16.0f);        // == floor((x+1)/2*32)
    float xmin = idf * 0.0625f - 1.0f;               // == idf/32*2-1 (exact)
    float xin  = (xe - xmin) * 32.0f - 1.0f;         // == 2*(x-xmin)/0.0625-1

    // t_m = xin - X_m
    float t0 = xin + 1.0f;
    float t1 = xin + 0.5f;
    float t2 = xin;
    float t3 = xin - 0.5f;
    float t4 = xin - 1.0f;

    // numerators via prefix/suffix products (denominators folded into w)
    float p1 = t0;
    float p2 = p1 * t1;
    float p3 = p2 * t2;
    float p4 = p3 * t3;
    float s3 = t4;
    float s2 = s3 * t3;
    float s1 = s2 * t2;
    float s0 = s1 * t1;

    float fx = s0 * w0;            // n0 = 1 * s0
    fx = fmaf(p1 * s1, w1, fx);
    fx = fmaf(p2 * s2, w2, fx);
    fx = fmaf(p3 * s3, w3, fx);
    fx = fmaf(p4,      w4, fx);    // n4 = p4 * 1
    return fx;
}

template <bool TR>
__global__ __launch_bounds__(256) void pdp_main(const float* __restrict__ x,
                                                const float* __restrict__ wsrc,
                                                float* __restrict__ out,
                                                int rows) {
    const int lane = threadIdx.x & 63;
    const int wv   = threadIdx.x >> 6;     // 4 waves/block -> 4 rows/iter
    const int f0   = lane << 2;            // this lane's first feature

    for (int b = blockIdx.x * 4 + wv; b < rows; b += gridDim.x * 4) {
        // streaming read: touched exactly once -> nontemporal
        const f32x4 xv = __builtin_nontemporal_load(
            reinterpret_cast<const f32x4*>(x + (size_t)b * IN_F + f0));

        // row segment from feature 0 (lane 0 holds it) -- wave-uniform
        float x0  = __shfl(xv.x, 0);
        int   seg = (int)floorf((x0 + 1.0f) * 16.0f);

        float wf[NNODE][4];
        if constexpr (TR) {
            // coalesced: wt[(seg*5+j)*256 + f], prescaled by c_j (cached path)
            const float* p = wsrc + (size_t)(seg * NNODE) * IN_F + f0;
#pragma unroll
            for (int j = 0; j < NNODE; ++j) {
                f32x4 t = *reinterpret_cast<const f32x4*>(p + j * IN_F);
                wf[j][0] = t.x; wf[j][1] = t.y; wf[j][2] = t.z; wf[j][3] = t.w;
            }
        } else {
            // fallback (no workspace): direct strided gather, scale in-kernel
            const float C0 = 2.0f / 3.0f, C1 = -8.0f / 3.0f, C2 = 4.0f;
#pragma unroll
            for (int fi = 0; fi < 4; ++fi) {
                const float* p = wsrc + (size_t)(f0 + fi) * NW + seg * NNODE;
                wf[0][fi] = p[0] * C0;
                wf[1][fi] = p[1] * C1;
                wf[2][fi] = p[2] * C2;
                wf[3][fi] = p[3] * C1;
                wf[4][fi] = p[4] * C0;
            }
        }

        f32x4 o;
        o.x = pdp_eval(xv.x, wf[0][0], wf[1][0], wf[2][0], wf[3][0], wf[4][0]);
        o.y = pdp_eval(xv.y, wf[0][1], wf[1][1], wf[2][1], wf[3][1], wf[4][1]);
        o.z = pdp_eval(xv.z, wf[0][2], wf[1][2], wf[2][2], wf[3][2], wf[4][2]);
        o.w = pdp_eval(xv.w, wf[0][3], wf[1][3], wf[2][3], wf[3][3], wf[4][3]);

        // streaming write: write-once -> nontemporal
        __builtin_nontemporal_store(
            o, reinterpret_cast<f32x4*>(out + (size_t)b * IN_F + f0));
    }
}

extern "C" void kernel_launch(void* const* d_in, const int* in_sizes, int n_in,
                              void* d_out, int out_size, void* d_ws, size_t ws_size,
                              hipStream_t stream) {
    const float* x = (const float*)d_in[0];
    const float* w = (const float*)d_in[1];
    float* out = (float*)d_out;

    const int B = in_sizes[0] / IN_F;   // 32768

    // grid: cap ~2048 blocks, grid-stride over rows (4 rows per block-iter)
    int nblk = (B + 3) / 4;
    if (nblk > 2048) nblk = 2048;

    const size_t wt_bytes = (size_t)USED_COLS * IN_F * sizeof(float);  // 160 KB
    if (ws_size >= wt_bytes) {
        float* wt = (float*)d_ws;
        const int total = USED_COLS * IN_F;
        pdp_prep<<<(total + 255) / 256, 256, 0, stream>>>(w, wt);
        pdp_main<true><<<nblk, 256, 0, stream>>>(x, wt, out, B);
    } else {
        pdp_main<false><<<nblk, 256, 0, stream>>>(x, w, out, B);
    }
}

// Round 6
// 114.854 us; speedup vs baseline: 1.0137x; 1.0137x over previous
//
#include <hip/hip_runtime.h>

// PiecewiseDiscontinuousPolynomial
//   x: (B=32768, F=256) f32 in [-1,1)
//   w: (F=256, 40960) f32 -- only columns [0,160) ever used:
//      cols = id_min[b,0]*5 + j,  id_min[b,0] in [0,32)
//   out[b,f] = sum_j basis_j(x_in[b,f]) * w[f, seg0(b)*5+j]
//
// R5 evidence: top-5 dispatches by dur are the harness's 41us ws-poison
// fills -> both our kernels run <41us; dur_us=116 includes ~70us of
// harness reset work. Addressable: main's dependent chain
// x-load(HBM ~900cy) -> shfl -> wt-load(L2 ~200cy) -> compute, exposed
// once per grid-stride iteration (4 iters/wave).
// R6 change: software-pipeline the x load (prefetch next iteration's xv
// before consuming the current one). Compute path bitwise-unchanged.

#define IN_F  256
#define NW    40960   // w leading dimension (columns)
#define NSEG  32
#define NNODE 5
#define USED_COLS (NSEG * NNODE)   // 160

typedef float f32x4 __attribute__((ext_vector_type(4)));

__global__ __launch_bounds__(256) void pdp_prep(const float* __restrict__ w,
                                                float* __restrict__ wt) {
    int tid = blockIdx.x * blockDim.x + threadIdx.x;
    if (tid >= USED_COLS * IN_F) return;
    int f = tid / USED_COLS;   // 0..255
    int c = tid % USED_COLS;   // 0..159  (reads contiguous in c per f)
    int j = c % NNODE;
    // c_j = 1 / prod_{m!=j}(X_j - X_m),  X = {-1,-0.5,0,0.5,1}
    float cj = (j == 2) ? 4.0f : ((j == 1 || j == 3) ? (-8.0f / 3.0f) : (2.0f / 3.0f));
    wt[c * IN_F + f] = w[(size_t)f * NW + c] * cj;
}

__device__ __forceinline__ float pdp_eval(float xe,
                                          float w0, float w1, float w2,
                                          float w3, float w4) {
    // bitwise == reference: all scalings are exact powers of two
    float idf  = floorf((xe + 1.0f) * 16.0f);        // == floor((x+1)/2*32)
    float xmin = idf * 0.0625f - 1.0f;               // exact
    float xin  = (xe - xmin) * 32.0f - 1.0f;         // exact

    float t0 = xin + 1.0f;
    float t1 = xin + 0.5f;
    float t2 = xin;
    float t3 = xin - 0.5f;
    float t4 = xin - 1.0f;

    // numerators via prefix/suffix products (denominators folded into w)
    float p1 = t0;
    float p2 = p1 * t1;
    float p3 = p2 * t2;
    float p4 = p3 * t3;
    float s3 = t4;
    float s2 = s3 * t3;
    float s1 = s2 * t2;
    float s0 = s1 * t1;

    float fx = s0 * w0;
    fx = fmaf(p1 * s1, w1, fx);
    fx = fmaf(p2 * s2, w2, fx);
    fx = fmaf(p3 * s3, w3, fx);
    fx = fmaf(p4,      w4, fx);
    return fx;
}

template <bool TR>
__global__ __launch_bounds__(256) void pdp_main(const float* __restrict__ x,
                                                const float* __restrict__ wsrc,
                                                float* __restrict__ out,
                                                int rows) {
    const int lane   = threadIdx.x & 63;
    const int wv     = threadIdx.x >> 6;   // 4 waves/block -> 4 rows/iter
    const int f0     = lane << 2;          // this lane's first feature
    const int stride = gridDim.x * 4;

    int b = blockIdx.x * 4 + wv;
    if (b >= rows) return;

    // pipeline prologue: first x load
    f32x4 xv = __builtin_nontemporal_load(
        reinterpret_cast<const f32x4*>(x + (size_t)b * IN_F + f0));

    while (true) {
        // issue next iteration's x load BEFORE consuming xv (wave-uniform branch)
        const int bn = b + stride;
        const bool have_next = bn < rows;
        f32x4 xn;
        if (have_next)
            xn = __builtin_nontemporal_load(
                reinterpret_cast<const f32x4*>(x + (size_t)bn * IN_F + f0));

        // row segment from feature 0 (lane 0 holds it) -- wave-uniform
        float x0  = __shfl(xv.x, 0);
        int   seg = (int)floorf((x0 + 1.0f) * 16.0f);

        float wf[NNODE][4];
        if constexpr (TR) {
            // coalesced: wt[(seg*5+j)*256 + f], prescaled by c_j (cached path)
            const float* p = wsrc + (size_t)(seg * NNODE) * IN_F + f0;
#pragma unroll
            for (int j = 0; j < NNODE; ++j) {
                f32x4 t = *reinterpret_cast<const f32x4*>(p + j * IN_F);
                wf[j][0] = t.x; wf[j][1] = t.y; wf[j][2] = t.z; wf[j][3] = t.w;
            }
        } else {
            // fallback (no workspace): direct strided gather, scale in-kernel
            const float C0 = 2.0f / 3.0f, C1 = -8.0f / 3.0f, C2 = 4.0f;
#pragma unroll
            for (int fi = 0; fi < 4; ++fi) {
                const float* p = wsrc + (size_t)(f0 + fi) * NW + seg * NNODE;
                wf[0][fi] = p[0] * C0;
                wf[1][fi] = p[1] * C1;
                wf[2][fi] = p[2] * C2;
                wf[3][fi] = p[3] * C1;
                wf[4][fi] = p[4] * C0;
            }
        }

        f32x4 o;
        o.x = pdp_eval(xv.x, wf[0][0], wf[1][0], wf[2][0], wf[3][0], wf[4][0]);
        o.y = pdp_eval(xv.y, wf[0][1], wf[1][1], wf[2][1], wf[3][1], wf[4][1]);
        o.z = pdp_eval(xv.z, wf[0][2], wf[1][2], wf[2][2], wf[3][2], wf[4][2]);
        o.w = pdp_eval(xv.w, wf[0][3], wf[1][3], wf[2][3], wf[3][3], wf[4][3]);

        __builtin_nontemporal_store(
            o, reinterpret_cast<f32x4*>(out + (size_t)b * IN_F + f0));

        if (!have_next) break;
        xv = xn;
        b  = bn;
    }
}

extern "C" void kernel_launch(void* const* d_in, const int* in_sizes, int n_in,
                              void* d_out, int out_size, void* d_ws, size_t ws_size,
                              hipStream_t stream) {
    const float* x = (const float*)d_in[0];
    const float* w = (const float*)d_in[1];
    float* out = (float*)d_out;

    const int B = in_sizes[0] / IN_F;   // 32768

    // grid: cap ~2048 blocks, grid-stride over rows (4 rows per block-iter)
    int nblk = (B + 3) / 4;
    if (nblk > 2048) nblk = 2048;

    const size_t wt_bytes = (size_t)USED_COLS * IN_F * sizeof(float);  // 160 KB
    if (ws_size >= wt_bytes) {
        float* wt = (float*)d_ws;
        const int total = USED_COLS * IN_F;
        pdp_prep<<<(total + 255) / 256, 256, 0, stream>>>(w, wt);
        pdp_main<true><<<nblk, 256, 0, stream>>>(x, wt, out, B);
    } else {
        pdp_main<false><<<nblk, 256, 0, stream>>>(x, w, out, B);
    }
}